// Round 11
// baseline (814.616 us; speedup 1.0000x reference)
//
#include <hip/hip_runtime.h>
#include <math.h>

#define LSEQ 2048
#define NB 8
#define NCH 64
#define NTOT (NB*NCH*LSEQ)   // 1048576
#define NROWS (NB*NCH)       // 512

typedef __attribute__((ext_vector_type(8))) short short8;
typedef __attribute__((ext_vector_type(4))) float float4v;

__device__ __forceinline__ float geluf(float x){
    return 0.5f*x*(1.0f+erff(x*0.70710678118654752f));
}
__device__ __forceinline__ float siluf(float x){
    return x/(1.0f+expf(-x));
}
__device__ __forceinline__ float sigf(float x){
    return 1.0f/(1.0f+expf(-x));
}
// fast gelu: A&S 7.1.26 erf (|err|<=1.5e-7) with v_exp/v_rcp — ODE path only
__device__ __forceinline__ float fast_gelu(float x){
    float z  = x*0.70710678118654752f;
    float az = fabsf(z);
    float t  = __builtin_amdgcn_rcpf(1.0f + 0.3275911f*az);
    float poly = t*(0.254829592f + t*(-0.284496736f + t*(1.421413741f
               + t*(-1.453152027f + t*1.061405429f))));
    float e  = __expf(-az*az);
    float r  = 1.0f - poly*e;
    float erfv = (z<0.f)? -r : r;
    return 0.5f*x*(1.0f+erfv);
}
__device__ __forceinline__ float fast_silu(float x){
    return x*__builtin_amdgcn_rcpf(1.0f+__expf(-x));
}
__device__ __forceinline__ unsigned short f2bf(float f){
    unsigned u=__float_as_uint(f);
    u += 0x7fffu + ((u>>16)&1u);
    return (unsigned short)(u>>16);
}
__device__ __forceinline__ float bf2f(unsigned h){
    return __uint_as_float((h&0xffffu)<<16);
}
// pack 2 fp32 -> 2 bf16 (RTNE) in one VALU op
__device__ __forceinline__ unsigned pk2bf(float a, float b){
    unsigned r;
    asm("v_cvt_pk_bf16_f32 %0, %1, %2" : "=v"(r) : "v"(a), "v"(b));
    return r;
}
// ODE LDS row offset: 36-dword rows + 4-dword shift every other 8-row group.
// Granule class (4-dword) of a b128 read = (rr + b8(rr) + 4ks + quad) mod 8;
// +8 rows always flips bit3 -> n vs n+8 land 4 apart -> exactly 8 lanes per
// class with distinct rows = bank-minimum (fixes the 8.06M conflict cycles;
// a within-row XOR cannot, since 8*rowstride == 0 mod 8 granules).
__device__ __forceinline__ int rofs(int r){
    return r*36 + ((r>>3)&1)*4;
}

// ---------------- weight transpose: w[64][64][3] -> wt[192][64] (gate) ------
__global__ __launch_bounds__(256) void wtrans_kernel(const float* __restrict__ w,
                                                     float* __restrict__ wt){
    int idx = blockIdx.x*256 + threadIdx.x;   // 12288 total
    int j = idx >> 6, co = idx & 63;
    wt[idx] = w[co*192 + j];
}

// ---- ode weight split-prep: WB[lvl][st][hl][tap][co][ci] bf16 --------------
__global__ __launch_bounds__(256) void wprep_kernel(const float* __restrict__ c1w,
                                                    const float* __restrict__ c2w,
                                                    short* __restrict__ WB){
    int idx = blockIdx.x*256 + threadIdx.x;   // 4*2*3*64*64 = 196608
    if (idx >= 196608) return;
    int ci  = idx & 63;
    int co  = (idx>>6) & 63;
    int tap = (idx>>12) % 3;
    int st  = (idx/(3<<12)) & 1;
    int lvl = idx/(6<<12);
    const float* src = (st==0? c1w : c2w);
    float w = src[(size_t)lvl*12288 + co*192 + ci*3 + tap];
    unsigned short hi = f2bf(w);
    float lo = w - bf2f(hi);
    size_t base = ((((size_t)(lvl*2+st)*2+0)*3+tap)*64+co)*64+ci;
    size_t basl = ((((size_t)(lvl*2+st)*2+1)*3+tap)*64+co)*64+ci;
    WB[base] = (short)hi;
    WB[basl] = (short)f2bf(lo);
}

// ------- stat = ROW SUMS over L; also zeroes the two rotation buffers -------
__global__ __launch_bounds__(256) void stat_kernel(const float* __restrict__ in,
                                                   float* __restrict__ stat,
                                                   float* __restrict__ stat1,
                                                   float* __restrict__ stat2){
    int r = blockIdx.x, tid = threadIdx.x;
    const float* p = in + (size_t)r*LSEQ;
    float acc = 0.f;
    for (int i=tid;i<LSEQ;i+=256) acc += p[i];
    for (int o=32;o>0;o>>=1) acc += __shfl_down(acc,o,64);
    __shared__ float red[4];
    if ((tid&63)==0) red[tid>>6]=acc;
    __syncthreads();
    if (tid==0){
        stat[r] = red[0]+red[1]+red[2]+red[3];
        stat1[r]=0.f;
        stat2[r]=0.f;
    }
}

// -------- filt + inline per-batch dywan MLP (dywan launches removed) --------
// Each block computes its OWN batch's filters from statin (55 MAC/thread MLP,
// deterministic/redundant across blocks), then does the 7-tap edge-pad conv.
// stat_out (if non-null) accumulates next level's row sums (3-buffer rotation;
// buffers pre-zeroed by stat_kernel). Ortho moved to tg_finalize.
__global__ __launch_bounds__(256) void filt_kernel(
    const float* __restrict__ ap, const float* __restrict__ statin,
    const float* __restrict__ w1, const float* __restrict__ b1,
    const float* __restrict__ wg1, const float* __restrict__ bg1,
    const float* __restrict__ wg2, const float* __restrict__ bg2,
    float* __restrict__ na, float* __restrict__ det,
    float* __restrict__ stat_out)
{
    int r = blockIdx.y, l0 = blockIdx.x*256, tid = threadIdx.x;
    int b = r>>6;
    __shared__ float s[262];
    __shared__ float st[64], h1[64], h2[128];
    __shared__ float fl[7], fh[7];
    __shared__ float sred[4];
    for (int idx=tid; idx<262; idx+=256){
        int l = l0+idx-3;
        l = min(max(l,0),LSEQ-1);
        s[idx]=ap[(size_t)r*LSEQ+l];
    }
    if (tid<64) st[tid]=statin[b*64+tid]*(1.0f/LSEQ);
    __syncthreads();
    if (tid<64){
        float acc=b1[tid];
        const float* W=w1+tid*64;
        for (int i=0;i<64;i++) acc += st[i]*W[i];
        h1[tid]=geluf(acc);
    }
    __syncthreads();
    if (tid<128){
        float acc=bg1[tid];
        const float* W=wg1+tid*64;
        for (int i=0;i<64;i++) acc += h1[i]*W[i];
        h2[tid]=geluf(acc);
    }
    __syncthreads();
    if (tid<14){
        float acc=bg2[tid];
        const float* W=wg2+tid*128;
        for (int i=0;i<128;i++) acc += h2[i]*W[i];
        if (tid<7) fl[tid]=acc; else fh[tid-7]=acc;
    }
    __syncthreads();
    float a=0.f, d=0.f;
    #pragma unroll
    for (int k=0;k<7;k++){ float v=s[tid+k]; a+=v*fl[k]; d+=v*fh[k]; }
    na[(size_t)r*LSEQ+l0+tid]=a;
    det[(size_t)r*LSEQ+l0+tid]=d;
    if (stat_out){
        float sm=a;
        for (int o=32;o>0;o>>=1) sm += __shfl_down(sm,o,64);
        if ((tid&63)==0) sred[tid>>6]=sm;
        __syncthreads();
        if (tid==0) atomicAdd(&stat_out[r], sred[0]+sred[1]+sred[2]+sred[3]);
    }
}

// ---------------- time grid pass1: per-row stats (batched over levels) ------
__global__ __launch_bounds__(256) void tg_pass1(const float* __restrict__ CB,
                                                float* __restrict__ rowstats){
    __shared__ float sh[2048];
    __shared__ float red[28];
    int r = blockIdx.x, lvl = blockIdx.y, tid = threadIdx.x;
    const float* s = CB + (size_t)lvl*NTOT + (size_t)r*LSEQ;
    float* rso = rowstats + (size_t)(lvl*NROWS+r)*8;
    for (int i=tid;i<2048;i+=256) sh[i]=s[i];
    __syncthreads();
    float ssq=0.f;
    for (int i=tid;i<2048;i+=256){ float v=sh[i]; ssq+=v*v; }
    float mn=1e30f, mx=-1e30f, s0=0.f,s1=0.f,s2=0.f,s3=0.f;
    for (int j=tid;j<2047;j+=256){
        int k0 = (j-2>0)? j-2:0;
        int k1 = (j+2<2046)? j+2:2046;
        float acc=0.f;
        for (int k=k0;k<=k1;k++) acc += fabsf(sh[k+1]-sh[k]);
        float inten = acc*0.2f;
        mn=fminf(mn,inten); mx=fmaxf(mx,inten);
        if (j<511)  s0+=inten;
        if (j<1023) s1+=inten;
        if (j<1534) s2+=inten;
        if (j<2046) s3+=inten;
    }
    float vals[7]={mn,mx,s0,s1,s2,s3,ssq};
    for (int o=32;o>0;o>>=1){
        vals[0]=fminf(vals[0],__shfl_down(vals[0],o,64));
        vals[1]=fmaxf(vals[1],__shfl_down(vals[1],o,64));
        vals[2]+=__shfl_down(vals[2],o,64);
        vals[3]+=__shfl_down(vals[3],o,64);
        vals[4]+=__shfl_down(vals[4],o,64);
        vals[5]+=__shfl_down(vals[5],o,64);
        vals[6]+=__shfl_down(vals[6],o,64);
    }
    int lane=tid&63, w=tid>>6;
    if (lane==0) for (int q=0;q<7;q++) red[w*7+q]=vals[q];
    __syncthreads();
    if (tid==0){
        rso[0]=fminf(fminf(red[0],red[7]),fminf(red[14],red[21]));
        rso[1]=fmaxf(fmaxf(red[1],red[8]),fmaxf(red[15],red[22]));
        rso[2]=red[2]+red[9]+red[16]+red[23];
        rso[3]=red[3]+red[10]+red[17]+red[24];
        rso[4]=red[4]+red[11]+red[18]+red[25];
        rso[5]=red[5]+red[12]+red[19]+red[26];
        rso[6]=red[6]+red[13]+red[20]+red[27];
    }
}

// ------- time grid finalize + modulation + ortho (grid = 4 levels) ----------
// Block lvl==0 additionally computes the level-2 dywan ortho from stat2
// (read-only by then) — replaces the 3 single-block dywan launches.
__global__ __launch_bounds__(256) void tg_finalize(
    const float* __restrict__ rowstats,
    const float* __restrict__ wt, const float* __restrict__ bt,
    const float* __restrict__ wm, const float* __restrict__ bm,
    const float* __restrict__ emb,
    const float* __restrict__ statin,
    const float* __restrict__ w1, const float* __restrict__ b1,
    const float* __restrict__ wg1, const float* __restrict__ bg1,
    const float* __restrict__ wg2, const float* __restrict__ bg2,
    float* __restrict__ ts_out, float* __restrict__ modsc,
    float* __restrict__ modbi, float* __restrict__ ein,
    float* __restrict__ eout, float* __restrict__ ortho_out)
{
    int tid=threadIdx.x;
    const int lvl=blockIdx.x;
    const float* rs = rowstats + (size_t)lvl*NROWS*8;
    __shared__ float red[28];
    __shared__ float stv[9];
    __shared__ float temb[144];
    __shared__ float sto[512];
    __shared__ float h1o[512];
    __shared__ float h2o[1024];
    __shared__ float fso[112];
    float mn=1e30f,mx=-1e30f,a0=0.f,a1=0.f,a2=0.f,a3=0.f,m3=-1e30f;
    for (int r=tid;r<512;r+=256){
        mn=fminf(mn,rs[r*8+0]); mx=fmaxf(mx,rs[r*8+1]);
        a0+=rs[r*8+2]; a1+=rs[r*8+3]; a2+=rs[r*8+4]; a3+=rs[r*8+5];
        m3=fmaxf(m3,rs[r*8+5]);
    }
    float vals[7]={mn,mx,a0,a1,a2,a3,m3};
    for (int o=32;o>0;o>>=1){
        vals[0]=fminf(vals[0],__shfl_down(vals[0],o,64));
        vals[1]=fmaxf(vals[1],__shfl_down(vals[1],o,64));
        vals[2]+=__shfl_down(vals[2],o,64);
        vals[3]+=__shfl_down(vals[3],o,64);
        vals[4]+=__shfl_down(vals[4],o,64);
        vals[5]+=__shfl_down(vals[5],o,64);
        vals[6]=fmaxf(vals[6],__shfl_down(vals[6],o,64));
    }
    int lane=tid&63, w=tid>>6;
    if (lane==0) for (int q=0;q<7;q++) red[w*7+q]=vals[q];
    if (tid<8){
        float e=0.f;
        for (int c=0;c<64;c++) e += rs[(tid*64+c)*8+6];
        ein[lvl*8+tid]=e*(1.0f/131072.0f);
        eout[lvl*8+tid]=0.f;
    }
    __syncthreads();
    if (tid==0){
        float mnv=fminf(fminf(red[0],red[7]),fminf(red[14],red[21]));
        float mxv=fmaxf(fmaxf(red[1],red[8]),fmaxf(red[15],red[22]));
        float s0=red[2]+red[9]+red[16]+red[23];
        float s1=red[3]+red[10]+red[17]+red[24];
        float s2=red[4]+red[11]+red[18]+red[25];
        float s3=red[5]+red[12]+red[19]+red[26];
        float m3v=fmaxf(fmaxf(red[6],red[13]),fmaxf(red[20],red[27]));
        const float idxs[5]={0.f,511.f,1023.f,1534.f,2046.f};
        float tsv[5];
        if (mxv-mnv < 1e-8f){
            for (int k=0;k<5;k++) tsv[k]=idxs[k]/2046.0f;
        } else {
            float a = 0.9f/(mxv-mnv+1e-30f);
            float bb = 0.1f - a*mnv;
            float gmax = a*m3v + bb*2046.0f;
            float sums[5]={0.f,s0,s1,s2,s3};
            tsv[0]=0.f;
            for (int k=1;k<5;k++)
                tsv[k]=(a*(sums[k]*(1.0f/512.0f)) + bb*idxs[k])/gmax;
        }
        for (int k=0;k<5;k++){ ts_out[lvl*8+k]=tsv[k]; stv[2*k]=tsv[k]; }
        for (int k=0;k<4;k++) stv[2*k+1]=tsv[k] + 0.5f*(tsv[k+1]-tsv[k]);
    }
    __syncthreads();
    if (tid<144){
        int m=tid>>4, i=tid&15;
        float z = wt[lvl*16+i]*stv[m] + bt[lvl*16+i];
        temb[tid]=siluf(z);
    }
    __syncthreads();
    for (int idx=tid; idx<1152; idx+=256){
        int m=idx>>7, c=idx&127;
        float g=bm[lvl*128+c];
        const float* W=wm+(size_t)(lvl*128+c)*16;
        const float* te=temb+m*16;
        for (int i=0;i<16;i++) g += W[i]*te[i];
        if (c<64) modsc[lvl*576+m*64+c]=1.0f+g+emb[(lvl*8+lvl)*64+c];
        else      modbi[lvl*576+m*64+(c-64)]=g;
    }
    // ---- ortho: full level-2 dywan MLP + regularizers (block lvl==0) ----
    if (lvl==0){
        for (int i=tid;i<512;i+=256) sto[i]=statin[i]*(1.0f/LSEQ);
        __syncthreads();
        for (int idx=tid; idx<512; idx+=256){
            int b=idx>>6, j=idx&63;
            float acc=b1[j];
            const float* W=w1+j*64;
            for (int i=0;i<64;i++) acc += sto[b*64+i]*W[i];
            h1o[idx]=geluf(acc);
        }
        __syncthreads();
        for (int idx=tid; idx<1024; idx+=256){
            int b=idx>>7, j=idx&127;
            float acc=bg1[j];
            const float* W=wg1+j*64;
            for (int i=0;i<64;i++) acc += h1o[b*64+i]*W[i];
            h2o[idx]=geluf(acc);
        }
        __syncthreads();
        if (tid<112){
            int b=tid/14, j=tid-b*14;
            float acc=bg2[j];
            const float* W=wg2+j*128;
            for (int i=0;i<128;i++) acc += h2o[b*128+i]*W[i];
            fso[tid]=acc;
        }
        __syncthreads();
        if (tid==0){
            float smooth=0.f, shiftsum=0.f, ampsum=0.f;
            for (int b=0;b<8;b++){
                const float* l = fso + b*14;   // lo row
                float prev=0.f, nrm=0.f;
                for (int k=0;k<7;k++){ smooth += fabsf(l[k]-prev); prev=l[k]; nrm += l[k]*l[k]; }
                smooth += fabsf(prev);
                float denom = sqrtf(nrm) + 1e-8f;
                float sabs=0.f, s2=0.f;
                for (int k=0;k<7;k++){ float v=l[k]/denom; sabs+=fabsf(v); s2+=v*v; }
                shiftsum += sabs*sabs;
                ampsum += fabsf(s2-1.0f);
            }
            smooth *= (1.0f/64.0f);
            float shift = 3.0f*shiftsum/(8.0f*49.0f);
            float amp = ampsum*(1.0f/8.0f);
            *ortho_out = 0.01f*(shift+amp) + 0.1f*smooth;
        }
    }
}

// ---------------- MFMA fused FULL RK4 step, 32-pos tiles --------------------
// grid (64, 8, 4): (32-pos tile, batch, level). block 256 = 4 waves.
// Tile frame: row R in [0,48) <-> pos l0-8+R. Central output R in [8,40).
// Halo shrinks 2/side per eval: k_e valid on R in [2e+2, 46-2e).
// R9 structure (verified: VGPR 84, FETCH 45 MB, 106 us) + rofs() row offset
// (period-16 granule shift; see rofs comment) to remove the 8.06M bank-
// conflict cycles that a within-row XOR cannot (R8 lesson).
// Ledger: (256,4)/(256,5) -> scratch spill; ye-in-regs -> spill; fast_gelu/
// fast_silu/pk2bf verified good (R9); persistent weights verified good (R4).
__global__ __launch_bounds__(256,3) void ode_rk4_step(
    const float* __restrict__ yinB, float* __restrict__ youtB,
    const short* __restrict__ WB, const float* __restrict__ c1bB,
    const float* __restrict__ c2bB,
    const float* __restrict__ modscB, const float* __restrict__ modbiB,
    const float* __restrict__ tsB, float* __restrict__ eoutB,
    int step, int do_energy)
{
    __shared__ unsigned Eh[1736], El[1736];   // current ye (bf16 hi/lo)
    __shared__ unsigned Hh[1736];             // conv1 output h (hi only)
    __shared__ float red[4];
    const int tid=threadIdx.x;
    const int lvl=blockIdx.z, b=blockIdx.y;
    const int l0=blockIdx.x*32;
    const size_t loff=(size_t)lvl*NTOT;
    const float* yin = yinB + loff;
    float* yout = youtB + loff;
    const float dt = tsB[lvl*8+step+1]-tsB[lvl*8+step];
    const float dt6 = dt*(1.0f/6.0f);
    const int wv=tid>>6, lane=tid&63;
    const int n=lane&15, quad=lane>>4;
    const int m0=wv*16;
    const int qy0=wv*8+quad*2;   // packed-pair col (dwords) for this thread

    // ---- stage y into split-bf16 tile (48 rows, zero-padded) ----
    if (lane<48){
        int r=lane, l=l0-8+r;
        bool ok=(l>=0 && l<LSEQ);
        unsigned hw[8], lw[8];
        #pragma unroll
        for (int qq=0;qq<8;qq++){
            int q=wv*8+qq;
            float v0=0.f, v1=0.f;
            if (ok){
                size_t g0=(size_t)(b*64+2*q)*LSEQ+l;
                v0=yin[g0]; v1=yin[g0+LSEQ];
            }
            unsigned h=pk2bf(v0,v1);
            float f0=__uint_as_float(h<<16);
            float f1=__uint_as_float(h&0xffff0000u);
            hw[qq]=h;
            lw[qq]=pk2bf(v0-f0, v1-f1);
        }
        int base = rofs(r) + wv*8;
        *(uint4*)&Eh[base]   = make_uint4(hw[0],hw[1],hw[2],hw[3]);
        *(uint4*)&Eh[base+4] = make_uint4(hw[4],hw[5],hw[6],hw[7]);
        *(uint4*)&El[base]   = make_uint4(lw[0],lw[1],lw[2],lw[3]);
        *(uint4*)&El[base+4] = make_uint4(lw[4],lw[5],lw[6],lw[7]);
    }

    // ---- persistent conv weights + biases (held across all 4 evals) ----
    const short* W1 = WB + (size_t)(lvl*2+0)*2*3*4096;
    const short* W2 = WB + (size_t)(lvl*2+1)*2*3*4096;
    short8 A1[3][2][2], A2[3][2][2];
    #pragma unroll
    for (int tap=0;tap<3;tap++)
        #pragma unroll
        for (int ks=0;ks<2;ks++)
            #pragma unroll
            for (int hl=0;hl<2;hl++){
                size_t off=(((size_t)hl*3+tap)*64+(m0+n))*64+ks*32+quad*8;
                A1[tap][ks][hl]=*(const short8*)(W1+off);
                A2[tap][ks][hl]=*(const short8*)(W2+off);
            }
    float bia[4], bib[4];
    #pragma unroll
    for (int reg=0;reg<4;reg++){
        bia[reg]=c1bB[lvl*64 + m0 + quad*4 + reg];
        bib[reg]=c2bB[lvl*64 + m0 + quad*4 + reg];
    }
    __syncthreads();

    // ---- own-cell original y in fp32 registers ----
    float yr[3][4], acc[3][4];
    #pragma unroll
    for (int nt=0;nt<3;nt++){
        int eb = rofs(16*nt+n) + qy0;
        uint2 hh=*(const uint2*)&Eh[eb];
        uint2 ll=*(const uint2*)&El[eb];
        yr[nt][0]=bf2f(hh.x)+bf2f(ll.x);
        yr[nt][1]=bf2f(hh.x>>16)+bf2f(ll.x>>16);
        yr[nt][2]=bf2f(hh.y)+bf2f(ll.y);
        yr[nt][3]=bf2f(hh.y>>16)+bf2f(ll.y>>16);
        #pragma unroll
        for (int reg=0;reg<4;reg++) acc[nt][reg]=0.f;
    }

    float esum=0.f;
    #pragma unroll 1
    for (int e=0;e<4;e++){
        const int hLo=2*e+1, hHi=47-2*e;
        const int kLo=2*e+2, kHi=46-2*e;

        // ---- conv1 ----
        #pragma unroll
        for (int nt=0;nt<3;nt++){
            float4v d={bia[0],bia[1],bia[2],bia[3]};
            #pragma unroll
            for (int tap=0;tap<3;tap++){
                int rr=16*nt+n+tap-1;
                rr=(rr<0)?0:((rr>47)?47:rr);   // clamp (junk rows masked)
                int rb = rofs(rr);
                #pragma unroll
                for (int ks=0;ks<2;ks++){
                    short8 bh=*(const short8*)&Eh[rb+ks*16+quad*4];
                    short8 bl=*(const short8*)&El[rb+ks*16+quad*4];
                    d=__builtin_amdgcn_mfma_f32_16x16x32_bf16(A1[tap][ks][0],bh,d,0,0,0);
                    d=__builtin_amdgcn_mfma_f32_16x16x32_bf16(A1[tap][ks][0],bl,d,0,0,0);
                    d=__builtin_amdgcn_mfma_f32_16x16x32_bf16(A1[tap][ks][1],bh,d,0,0,0);
                }
            }
            int R=16*nt+n, hp=l0-8+R;
            bool okh=(R>=hLo && R<hHi && hp>=0 && hp<LSEQ);
            float h0=okh?fast_gelu(d[0]):0.f;
            float h1=okh?fast_gelu(d[1]):0.f;
            float h2=okh?fast_gelu(d[2]):0.f;
            float h3=okh?fast_gelu(d[3]):0.f;
            uint2 hv;
            hv.x=pk2bf(h0,h1);
            hv.y=pk2bf(h2,h3);
            *(uint2*)&Hh[rofs(R)+qy0]=hv;
        }
        __syncthreads();

        // ---- conv2 + epilogue (k fp32; ye from own LDS cells) ----
        {
            const int tslot=2*step+((e==0)?0:((e==3)?2:1));
            float sc[4], bi2[4];
            #pragma unroll
            for (int reg=0;reg<4;reg++){
                int co=m0+quad*4+reg;
                sc[reg] =modscB[lvl*576+tslot*64+co];
                bi2[reg]=modbiB[lvl*576+tslot*64+co];
            }
            const float alf=(e==2)?dt:0.5f*dt;
            const float wk=(e==0)?1.f:2.f;
            #pragma unroll
            for (int nt=0;nt<3;nt++){
                float4v d={bib[0],bib[1],bib[2],bib[3]};
                #pragma unroll
                for (int tap=0;tap<3;tap++){
                    int rr=16*nt+n+tap-1;
                    rr=(rr<0)?0:((rr>47)?47:rr);
                    int rb = rofs(rr);
                    #pragma unroll
                    for (int ks=0;ks<2;ks++){
                        short8 bh=*(const short8*)&Hh[rb+ks*16+quad*4];
                        d=__builtin_amdgcn_mfma_f32_16x16x32_bf16(A2[tap][ks][0],bh,d,0,0,0);
                        d=__builtin_amdgcn_mfma_f32_16x16x32_bf16(A2[tap][ks][1],bh,d,0,0,0);
                    }
                }
                int R=16*nt+n, p=l0-8+R;
                bool okk=(R>=kLo && R<kHi && p>=0 && p<LSEQ);
                bool central=(R>=8 && R<40);
                int eb = rofs(R) + qy0;
                // ye from own LDS cells (self-written, self-read: no race)
                uint2 hh=*(const uint2*)&Eh[eb];
                uint2 ll=*(const uint2*)&El[eb];
                float yev[4];
                yev[0]=bf2f(hh.x)+bf2f(ll.x);
                yev[1]=bf2f(hh.x>>16)+bf2f(ll.x>>16);
                yev[2]=bf2f(hh.y)+bf2f(ll.y);
                yev[3]=bf2f(hh.y>>16)+bf2f(ll.y>>16);
                float kv[4];
                #pragma unroll
                for (int reg=0;reg<4;reg++){
                    float m=d[reg]*sc[reg]+bi2[reg];
                    kv[reg]=fast_silu(m)-0.1f*yev[reg];
                }
                if (e<3){
                    float z[4];
                    #pragma unroll
                    for (int reg=0;reg<4;reg++)
                        z[reg]=okk?(yr[nt][reg]+alf*kv[reg]):0.f;
                    uint2 ev, lv;
                    ev.x=pk2bf(z[0],z[1]);
                    ev.y=pk2bf(z[2],z[3]);
                    float f0=__uint_as_float(ev.x<<16);
                    float f1=__uint_as_float(ev.x&0xffff0000u);
                    float f2=__uint_as_float(ev.y<<16);
                    float f3=__uint_as_float(ev.y&0xffff0000u);
                    lv.x=pk2bf(z[0]-f0, z[1]-f1);
                    lv.y=pk2bf(z[2]-f2, z[3]-f3);
                    *(uint2*)&Eh[eb]=ev;
                    *(uint2*)&El[eb]=lv;
                    if (central){
                        #pragma unroll
                        for (int reg=0;reg<4;reg++) acc[nt][reg]+=wk*kv[reg];
                    }
                } else if (central){
                    size_t gbase=(size_t)(b*64+m0+quad*4)*LSEQ+p;
                    #pragma unroll
                    for (int reg=0;reg<4;reg++){
                        float yn=yr[nt][reg]+dt6*(acc[nt][reg]+kv[reg]);
                        yout[gbase+(size_t)reg*LSEQ]=yn;
                        esum+=yn*yn;
                    }
                }
            }
        }
        __syncthreads();
    }
    if (do_energy){
        for (int o=32;o>0;o>>=1) esum+=__shfl_down(esum,o,64);
        if ((tid&63)==0) red[tid>>6]=esum;
        __syncthreads();
        if (tid==0) atomicAdd(&eoutB[lvl*8+b], red[0]+red[1]+red[2]+red[3]);
    }
}

// -------- fused reconstruction: scale + [attn] + gate + residual ------------
// grid (32, NB). cur scaled by s(lvl_cur) on load (if lvl_cur>=0);
// detail read from det_in scaled by s(lvl_det); final detail written to det_out.
__global__ __launch_bounds__(256) void recon_kernel(
    const float* __restrict__ cur, const float* __restrict__ det_in,
    float* __restrict__ det_out,
    const float* __restrict__ a1w, const float* __restrict__ a1b,
    const float* __restrict__ a2w, const float* __restrict__ a2b,
    const float* __restrict__ gwt, const float* __restrict__ gb,
    float* __restrict__ curout,
    const float* __restrict__ ein, const float* __restrict__ eout,
    int lvl_cur, int lvl_det, int has_attn)
{
    __shared__ float yc[64][66];
    __shared__ float dtile[64][65];
    __shared__ float hid[16][64];
    const int tid=threadIdx.x, b=blockIdx.y, l0=blockIdx.x*64;
    float scur=1.f, sdet;
    if (lvl_cur>=0){
        float eo=eout[lvl_cur*8+b]*(1.0f/131072.0f);
        scur=sqrtf(ein[lvl_cur*8+b]/(eo+1e-8f));
    }
    {
        float eo=eout[lvl_det*8+b]*(1.0f/131072.0f);
        sdet=sqrtf(ein[lvl_det*8+b]/(eo+1e-8f));
    }
    for (int idx=tid; idx<64*66; idx+=256){
        int ci=idx/66, u=idx-ci*66;
        int l=l0+u-1;
        yc[ci][u]=(l>=0 && l<LSEQ)? scur*cur[(size_t)(b*64+ci)*LSEQ+l] : 0.f;
    }
    for (int idx=tid; idx<4096; idx+=256){
        int ci=idx>>6, p=idx&63;
        dtile[ci][p]=sdet*det_in[(size_t)(b*64+ci)*LSEQ+l0+p];
    }
    __syncthreads();
    if (has_attn){
        for (int idx=tid; idx<1024; idx+=256){
            int h=idx>>6, p=idx&63;
            float acc=a1b[h];
            const float* W=a1w+h*64;
            for (int ci=0;ci<64;ci++) acc += W[ci]*yc[ci][p+1];
            hid[h][p]=geluf(acc);
        }
        __syncthreads();
        for (int idx=tid; idx<4096; idx+=256){
            int co=idx>>6, p=idx&63;
            float acc=a2b[co];
            const float* W=a2w+co*16;
            #pragma unroll
            for (int h=0;h<16;h++) acc += W[h]*hid[h][p];
            float a=sigf(acc);
            float dnew = dtile[co][p]*(1.0f+a);
            dtile[co][p]=dnew;
            det_out[(size_t)(b*64+co)*LSEQ+l0+p]=dnew;
        }
        __syncthreads();
    } else {
        for (int idx=tid; idx<4096; idx+=256){
            int ci=idx>>6, p=idx&63;
            det_out[(size_t)(b*64+ci)*LSEQ+l0+p]=dtile[ci][p];
        }
    }
    const int co=tid&63, g=tid>>6;
    const int p0=g*16;
    float a[16];
    float bb=gb[co];
    #pragma unroll
    for (int i=0;i<16;i++) a[i]=bb;
    for (int ci=0;ci<64;ci++){
        float w0=gwt[(ci*3+0)*64+co];
        float w1_=gwt[(ci*3+1)*64+co];
        float w2_=gwt[(ci*3+2)*64+co];
        float x[18];
        #pragma unroll
        for (int j=0;j<18;j++) x[j]=yc[ci][p0+j];
        #pragma unroll
        for (int i=0;i<16;i++) a[i] += w0*x[i]+w1_*x[i+1]+w2_*x[i+2];
    }
    float r[16];
    #pragma unroll
    for (int i=0;i<16;i++){
        float gt=sigf(a[i]);
        r[i]=yc[co][p0+i+1]+gt*dtile[co][p0+i];
    }
    __syncthreads();
    #pragma unroll
    for (int i=0;i<16;i++) dtile[co][p0+i]=r[i];
    __syncthreads();
    for (int idx=tid; idx<4096; idx+=256){
        int ci=idx>>6, p=idx&63;
        curout[(size_t)(b*64+ci)*LSEQ+l0+p]=dtile[ci][p];
    }
}

extern "C" void kernel_launch(void* const* d_in, const int* in_sizes, int n_in,
                              void* d_out, int out_size, void* d_ws, size_t ws_size,
                              hipStream_t stream)
{
    (void)in_sizes; (void)n_in; (void)out_size; (void)ws_size;
    const float* x       =(const float*)d_in[0];
    const float* dy_w1   =(const float*)d_in[1];
    const float* dy_b1   =(const float*)d_in[2];
    const float* dy_wg1  =(const float*)d_in[3];
    const float* dy_bg1  =(const float*)d_in[4];
    const float* dy_wg2  =(const float*)d_in[5];
    const float* dy_bg2  =(const float*)d_in[6];
    const float* ode_c1w =(const float*)d_in[7];
    const float* ode_c1b =(const float*)d_in[8];
    const float* ode_c2w =(const float*)d_in[9];
    const float* ode_c2b =(const float*)d_in[10];
    const float* ode_wt  =(const float*)d_in[11];
    const float* ode_bt  =(const float*)d_in[12];
    const float* ode_wm  =(const float*)d_in[13];
    const float* ode_bm  =(const float*)d_in[14];
    const float* ode_emb =(const float*)d_in[15];
    const float* gate_w  =(const float*)d_in[16];
    const float* gate_b  =(const float*)d_in[17];
    const float* attn1_w =(const float*)d_in[18];
    const float* attn1_b =(const float*)d_in[19];
    const float* attn2_w =(const float*)d_in[20];
    const float* attn2_b =(const float*)d_in[21];
    float* out=(float*)d_out;
    float* ws=(float*)d_ws;
    const size_t N=NTOT;
    // workspace layout (floats)
    float* CB = ws;                      // coeff[4]: A0, D1, D2, D3 (4N)
    float* PB = ws+4*N;                  // y ping (4 levels) — also decomp temps
    float* QB = ws+8*N;                  // y pong (4 levels)
    float* SB = ws+12*N;                 // stat rotation buffers (2*512)
    float* SM = ws+20*N;
    float* stat_ws =SM;          // 512 (S0)
    float* rowstats=SM+1024;     // 4*512*8 = 16384
    float* ts_ws   =SM+17408;    // 4*8
    float* modsc   =SM+17536;    // 4*576
    float* modbi   =SM+19840;    // 4*576
    float* ein     =SM+22144;    // 32
    float* eoutb   =SM+22176;    // 32
    short* WB      =(short*)(SM+24576);  // 393216 bf16 = 196608 floats
    float* WTG     =SM+24576+196608;     // 3*12288 (gate weights, transposed)
    float* stat1 = SB;           // 512 (S1)
    float* stat2 = SB+512;       // 512 (S2)

    dim3 blk(256);

    wprep_kernel<<<768,blk,0,stream>>>(ode_c1w, ode_c2w, WB);
    for (int i=0;i<3;i++)
        wtrans_kernel<<<48,blk,0,stream>>>(gate_w+(size_t)i*12288, WTG+(size_t)i*12288);

    // ---- wavelet decomposition (3 levels; dywan folded into filt) ----
    stat_kernel<<<NROWS,blk,0,stream>>>(x, stat_ws, stat1, stat2);
    const float* cura=x;
    float* outsA[3]={PB, PB+N, CB};      // T0, T1, A0-final
    float* outsD[3]={CB+N, CB+2*N, CB+3*N};
    const float* sins[3]={stat_ws, stat1, stat2};
    float* souts[3]={stat1, stat2, nullptr};
    for (int lv=0; lv<3; lv++){
        filt_kernel<<<dim3(8,NROWS),blk,0,stream>>>(cura, sins[lv],
            dy_w1, dy_b1, dy_wg1, dy_bg1, dy_wg2, dy_bg2,
            outsA[lv], outsD[lv], souts[lv]);
        cura=outsA[lv];
    }

    // ---- adaptive grids + modulation + ortho for all 4 levels ----
    tg_pass1<<<dim3(NROWS,4),blk,0,stream>>>(CB, rowstats);
    tg_finalize<<<4,blk,0,stream>>>(rowstats, ode_wt, ode_bt, ode_wm, ode_bm,
                                    ode_emb, stat2,
                                    dy_w1, dy_b1, dy_wg1, dy_bg1, dy_wg2, dy_bg2,
                                    ts_ws, modsc, modbi, ein, eoutb, out+4*N);

    // ---- RK4: 4 fused steps (each does all 4 evals in-block) ----
    const float* yins[4]={CB, PB, QB, PB};
    float*       youts[4]={PB, QB, PB, QB};
    for (int s=0;s<4;s++){
        ode_rk4_step<<<dim3(64,NB,4),blk,0,stream>>>(
            yins[s], youts[s], WB, ode_c1b, ode_c2b,
            modsc, modbi, ts_ws, eoutb, s, (s==3)?1:0);
    }

    // ---- reconstruction (fused scale+attn+gate); evolved lives in QB ----
    // i=2: cur=s0*QB0, detail=s3*QB3 -> out3; current -> PB
    recon_kernel<<<dim3(32,NB),blk,0,stream>>>(QB+0*N, QB+3*N, out+3*N,
        attn1_w, attn1_b, attn2_w, attn2_b,
        WTG+2*12288, gate_b+128, PB, ein, eoutb, 0, 3, 0);
    // i=1: cur=PB, detail=s2*QB2 + attn(set1) -> out2; current -> QB(slot0)
    recon_kernel<<<dim3(32,NB),blk,0,stream>>>(PB, QB+2*N, out+2*N,
        attn1_w+1024, attn1_b+16, attn2_w+1024, attn2_b+64,
        WTG+1*12288, gate_b+64, QB, ein, eoutb, -1, 2, 1);
    // i=0: cur=QB(slot0), detail=s1*QB1 + attn(set0) -> out1; current -> out0
    recon_kernel<<<dim3(32,NB),blk,0,stream>>>(QB, QB+1*N, out+1*N,
        attn1_w, attn1_b, attn2_w, attn2_b,
        WTG, gate_b, out+0*N, ein, eoutb, -1, 1, 1);
}

// Round 12
// 654.505 us; speedup vs baseline: 1.2446x; 1.2446x over previous
//
#include <hip/hip_runtime.h>
#include <math.h>

#define LSEQ 2048
#define NB 8
#define NCH 64
#define NTOT (NB*NCH*LSEQ)   // 1048576
#define NROWS (NB*NCH)       // 512

typedef __attribute__((ext_vector_type(8))) short short8;
typedef __attribute__((ext_vector_type(4))) float float4v;

__device__ __forceinline__ float geluf(float x){
    return 0.5f*x*(1.0f+erff(x*0.70710678118654752f));
}
__device__ __forceinline__ float siluf(float x){
    return x/(1.0f+expf(-x));
}
__device__ __forceinline__ float sigf(float x){
    return 1.0f/(1.0f+expf(-x));
}
// fast gelu: A&S 7.1.26 erf (|err|<=1.5e-7) with v_exp/v_rcp — ODE path only
__device__ __forceinline__ float fast_gelu(float x){
    float z  = x*0.70710678118654752f;
    float az = fabsf(z);
    float t  = __builtin_amdgcn_rcpf(1.0f + 0.3275911f*az);
    float poly = t*(0.254829592f + t*(-0.284496736f + t*(1.421413741f
               + t*(-1.453152027f + t*1.061405429f))));
    float e  = __expf(-az*az);
    float r  = 1.0f - poly*e;
    float erfv = (z<0.f)? -r : r;
    return 0.5f*x*(1.0f+erfv);
}
__device__ __forceinline__ float fast_silu(float x){
    return x*__builtin_amdgcn_rcpf(1.0f+__expf(-x));
}
__device__ __forceinline__ unsigned short f2bf(float f){
    unsigned u=__float_as_uint(f);
    u += 0x7fffu + ((u>>16)&1u);
    return (unsigned short)(u>>16);
}
__device__ __forceinline__ float bf2f(unsigned h){
    return __uint_as_float((h&0xffffu)<<16);
}
// pack 2 fp32 -> 2 bf16 (RTNE) in one VALU op
__device__ __forceinline__ unsigned pk2bf(float a, float b){
    unsigned r;
    asm("v_cvt_pk_bf16_f32 %0, %1, %2" : "=v"(r) : "v"(a), "v"(b));
    return r;
}

// ---------------- weight transpose: w[64][64][3] -> wt[192][64] (gate) ------
__global__ __launch_bounds__(256) void wtrans_kernel(const float* __restrict__ w,
                                                     float* __restrict__ wt){
    int idx = blockIdx.x*256 + threadIdx.x;   // 12288 total
    int j = idx >> 6, co = idx & 63;
    wt[idx] = w[co*192 + j];
}

// ---- ode weight split-prep: WB[lvl][st][hl][tap][co][ci] bf16 --------------
__global__ __launch_bounds__(256) void wprep_kernel(const float* __restrict__ c1w,
                                                    const float* __restrict__ c2w,
                                                    short* __restrict__ WB){
    int idx = blockIdx.x*256 + threadIdx.x;   // 4*2*3*64*64 = 196608
    if (idx >= 196608) return;
    int ci  = idx & 63;
    int co  = (idx>>6) & 63;
    int tap = (idx>>12) % 3;
    int st  = (idx/(3<<12)) & 1;
    int lvl = idx/(6<<12);
    const float* src = (st==0? c1w : c2w);
    float w = src[(size_t)lvl*12288 + co*192 + ci*3 + tap];
    unsigned short hi = f2bf(w);
    float lo = w - bf2f(hi);
    size_t base = ((((size_t)(lvl*2+st)*2+0)*3+tap)*64+co)*64+ci;
    size_t basl = ((((size_t)(lvl*2+st)*2+1)*3+tap)*64+co)*64+ci;
    WB[base] = (short)hi;
    WB[basl] = (short)f2bf(lo);
}

// ---------------- stat = ROW SUMS over L (dywan normalizes) -----------------
__global__ __launch_bounds__(256) void stat_kernel(const float* __restrict__ in,
                                                   float* __restrict__ stat){
    int r = blockIdx.x, tid = threadIdx.x;
    const float* p = in + (size_t)r*LSEQ;
    float acc = 0.f;
    for (int i=tid;i<LSEQ;i+=256) acc += p[i];
    for (int o=32;o>0;o>>=1) acc += __shfl_down(acc,o,64);
    __shared__ float red[4];
    if ((tid&63)==0) red[tid>>6]=acc;
    __syncthreads();
    if (tid==0) stat[r] = red[0]+red[1]+red[2]+red[3];
}

// ---------------- dywan MLP + filters + ortho (stat = raw sums) -------------
__global__ __launch_bounds__(256) void dywan_kernel(
    float* __restrict__ stat,
    const float* __restrict__ w1, const float* __restrict__ b1,
    const float* __restrict__ wg1, const float* __restrict__ bg1,
    const float* __restrict__ wg2, const float* __restrict__ bg2,
    float* __restrict__ lo_out, float* __restrict__ hi_out,
    float* __restrict__ ortho_out)
{
    __shared__ float st[512];
    __shared__ float h1s[512];
    __shared__ float h2s[1024];
    __shared__ float fs[112];
    int tid = threadIdx.x;
    for (int i=tid;i<512;i+=256) st[i]=stat[i]*(1.0f/LSEQ);
    __syncthreads();
    // reset stat accumulator for the next level's filt atomics
    for (int i=tid;i<512;i+=256) stat[i]=0.f;
    for (int idx=tid; idx<512; idx+=256){
        int b=idx>>6, j=idx&63;
        float acc=b1[j];
        const float* W=w1+j*64;
        for (int i=0;i<64;i++) acc += st[b*64+i]*W[i];
        h1s[idx]=geluf(acc);
    }
    __syncthreads();
    for (int idx=tid; idx<1024; idx+=256){
        int b=idx>>7, j=idx&127;
        float acc=bg1[j];
        const float* W=wg1+j*64;
        for (int i=0;i<64;i++) acc += h1s[b*64+i]*W[i];
        h2s[idx]=geluf(acc);
    }
    __syncthreads();
    if (tid<112){
        int b=tid/14, j=tid-b*14;
        float acc=bg2[j];
        const float* W=wg2+j*128;
        for (int i=0;i<128;i++) acc += h2s[b*128+i]*W[i];
        fs[tid]=acc;
    }
    __syncthreads();
    if (tid<56){
        int b=tid/7, k=tid-b*7;
        lo_out[tid]=fs[b*14+k];
        hi_out[tid]=fs[b*14+7+k];
    }
    if (tid==0){
        float smooth=0.f, shiftsum=0.f, ampsum=0.f;
        for (int b=0;b<8;b++){
            const float* l = fs + b*14;   // lo row
            float prev=0.f, nrm=0.f;
            for (int k=0;k<7;k++){ smooth += fabsf(l[k]-prev); prev=l[k]; nrm += l[k]*l[k]; }
            smooth += fabsf(prev);
            float denom = sqrtf(nrm) + 1e-8f;
            float sabs=0.f, s2=0.f;
            for (int k=0;k<7;k++){ float v=l[k]/denom; sabs+=fabsf(v); s2+=v*v; }
            shiftsum += sabs*sabs;
            ampsum += fabsf(s2-1.0f);
        }
        smooth *= (1.0f/64.0f);
        float shift = 3.0f*shiftsum/(8.0f*49.0f);
        float amp = ampsum*(1.0f/8.0f);
        *ortho_out = 0.01f*(shift+amp) + 0.1f*smooth;
    }
}

// -------- per-batch 7-tap filter conv (edge pad) + optional stat acc --------
__global__ __launch_bounds__(256) void filt_kernel(
    const float* __restrict__ ap, const float* __restrict__ lo,
    const float* __restrict__ hi, float* __restrict__ na,
    float* __restrict__ det, float* __restrict__ stat_out)
{
    int r = blockIdx.y, l0 = blockIdx.x*256, tid = threadIdx.x;
    int b = r>>6;
    __shared__ float s[262];
    __shared__ float fl[7], fh[7];
    __shared__ float sred[4];
    for (int idx=tid; idx<262; idx+=256){
        int l = l0+idx-3;
        l = min(max(l,0),LSEQ-1);
        s[idx]=ap[(size_t)r*LSEQ+l];
    }
    if (tid<7) fl[tid]=lo[b*7+tid];
    else if (tid<14) fh[tid-7]=hi[b*7+tid-7];
    __syncthreads();
    float a=0.f, d=0.f;
    #pragma unroll
    for (int k=0;k<7;k++){ float v=s[tid+k]; a+=v*fl[k]; d+=v*fh[k]; }
    na[(size_t)r*LSEQ+l0+tid]=a;
    det[(size_t)r*LSEQ+l0+tid]=d;
    if (stat_out){
        float sm=a;
        for (int o=32;o>0;o>>=1) sm += __shfl_down(sm,o,64);
        if ((tid&63)==0) sred[tid>>6]=sm;
        __syncthreads();
        if (tid==0) atomicAdd(&stat_out[r], sred[0]+sred[1]+sred[2]+sred[3]);
    }
}

// ---------------- time grid pass1: per-row stats (batched over levels) ------
__global__ __launch_bounds__(256) void tg_pass1(const float* __restrict__ CB,
                                                float* __restrict__ rowstats){
    __shared__ float sh[2048];
    __shared__ float red[28];
    int r = blockIdx.x, lvl = blockIdx.y, tid = threadIdx.x;
    const float* s = CB + (size_t)lvl*NTOT + (size_t)r*LSEQ;
    float* rso = rowstats + (size_t)(lvl*NROWS+r)*8;
    for (int i=tid;i<2048;i+=256) sh[i]=s[i];
    __syncthreads();
    float ssq=0.f;
    for (int i=tid;i<2048;i+=256){ float v=sh[i]; ssq+=v*v; }
    float mn=1e30f, mx=-1e30f, s0=0.f,s1=0.f,s2=0.f,s3=0.f;
    for (int j=tid;j<2047;j+=256){
        int k0 = (j-2>0)? j-2:0;
        int k1 = (j+2<2046)? j+2:2046;
        float acc=0.f;
        for (int k=k0;k<=k1;k++) acc += fabsf(sh[k+1]-sh[k]);
        float inten = acc*0.2f;
        mn=fminf(mn,inten); mx=fmaxf(mx,inten);
        if (j<511)  s0+=inten;
        if (j<1023) s1+=inten;
        if (j<1534) s2+=inten;
        if (j<2046) s3+=inten;
    }
    float vals[7]={mn,mx,s0,s1,s2,s3,ssq};
    for (int o=32;o>0;o>>=1){
        vals[0]=fminf(vals[0],__shfl_down(vals[0],o,64));
        vals[1]=fmaxf(vals[1],__shfl_down(vals[1],o,64));
        vals[2]+=__shfl_down(vals[2],o,64);
        vals[3]+=__shfl_down(vals[3],o,64);
        vals[4]+=__shfl_down(vals[4],o,64);
        vals[5]+=__shfl_down(vals[5],o,64);
        vals[6]+=__shfl_down(vals[6],o,64);
    }
    int lane=tid&63, w=tid>>6;
    if (lane==0) for (int q=0;q<7;q++) red[w*7+q]=vals[q];
    __syncthreads();
    if (tid==0){
        rso[0]=fminf(fminf(red[0],red[7]),fminf(red[14],red[21]));
        rso[1]=fmaxf(fmaxf(red[1],red[8]),fmaxf(red[15],red[22]));
        rso[2]=red[2]+red[9]+red[16]+red[23];
        rso[3]=red[3]+red[10]+red[17]+red[24];
        rso[4]=red[4]+red[11]+red[18]+red[25];
        rso[5]=red[5]+red[12]+red[19]+red[26];
        rso[6]=red[6]+red[13]+red[20]+red[27];
    }
}

// ---------------- time grid finalize + modulation (grid = 4 levels) ---------
__global__ __launch_bounds__(256) void tg_finalize(
    const float* __restrict__ rowstats,
    const float* __restrict__ wt, const float* __restrict__ bt,
    const float* __restrict__ wm, const float* __restrict__ bm,
    const float* __restrict__ emb,
    float* __restrict__ ts_out, float* __restrict__ modsc,
    float* __restrict__ modbi, float* __restrict__ ein,
    float* __restrict__ eout)
{
    int tid=threadIdx.x;
    const int lvl=blockIdx.x;
    const float* rs = rowstats + (size_t)lvl*NROWS*8;
    __shared__ float red[28];
    __shared__ float stv[9];
    __shared__ float temb[144];
    float mn=1e30f,mx=-1e30f,a0=0.f,a1=0.f,a2=0.f,a3=0.f,m3=-1e30f;
    for (int r=tid;r<512;r+=256){
        mn=fminf(mn,rs[r*8+0]); mx=fmaxf(mx,rs[r*8+1]);
        a0+=rs[r*8+2]; a1+=rs[r*8+3]; a2+=rs[r*8+4]; a3+=rs[r*8+5];
        m3=fmaxf(m3,rs[r*8+5]);
    }
    float vals[7]={mn,mx,a0,a1,a2,a3,m3};
    for (int o=32;o>0;o>>=1){
        vals[0]=fminf(vals[0],__shfl_down(vals[0],o,64));
        vals[1]=fmaxf(vals[1],__shfl_down(vals[1],o,64));
        vals[2]+=__shfl_down(vals[2],o,64);
        vals[3]+=__shfl_down(vals[3],o,64);
        vals[4]+=__shfl_down(vals[4],o,64);
        vals[5]+=__shfl_down(vals[5],o,64);
        vals[6]=fmaxf(vals[6],__shfl_down(vals[6],o,64));
    }
    int lane=tid&63, w=tid>>6;
    if (lane==0) for (int q=0;q<7;q++) red[w*7+q]=vals[q];
    if (tid<8){
        float e=0.f;
        for (int c=0;c<64;c++) e += rs[(tid*64+c)*8+6];
        ein[lvl*8+tid]=e*(1.0f/131072.0f);
        eout[lvl*8+tid]=0.f;
    }
    __syncthreads();
    if (tid==0){
        float mnv=fminf(fminf(red[0],red[7]),fminf(red[14],red[21]));
        float mxv=fmaxf(fmaxf(red[1],red[8]),fmaxf(red[15],red[22]));
        float s0=red[2]+red[9]+red[16]+red[23];
        float s1=red[3]+red[10]+red[17]+red[24];
        float s2=red[4]+red[11]+red[18]+red[25];
        float s3=red[5]+red[12]+red[19]+red[26];
        float m3v=fmaxf(fmaxf(red[6],red[13]),fmaxf(red[20],red[27]));
        const float idxs[5]={0.f,511.f,1023.f,1534.f,2046.f};
        float tsv[5];
        if (mxv-mnv < 1e-8f){
            for (int k=0;k<5;k++) tsv[k]=idxs[k]/2046.0f;
        } else {
            float a = 0.9f/(mxv-mnv+1e-30f);
            float bb = 0.1f - a*mnv;
            float gmax = a*m3v + bb*2046.0f;
            float sums[5]={0.f,s0,s1,s2,s3};
            tsv[0]=0.f;
            for (int k=1;k<5;k++)
                tsv[k]=(a*(sums[k]*(1.0f/512.0f)) + bb*idxs[k])/gmax;
        }
        for (int k=0;k<5;k++){ ts_out[lvl*8+k]=tsv[k]; stv[2*k]=tsv[k]; }
        for (int k=0;k<4;k++) stv[2*k+1]=tsv[k] + 0.5f*(tsv[k+1]-tsv[k]);
    }
    __syncthreads();
    if (tid<144){
        int m=tid>>4, i=tid&15;
        float z = wt[lvl*16+i]*stv[m] + bt[lvl*16+i];
        temb[tid]=siluf(z);
    }
    __syncthreads();
    for (int idx=tid; idx<1152; idx+=256){
        int m=idx>>7, c=idx&127;
        float g=bm[lvl*128+c];
        const float* W=wm+(size_t)(lvl*128+c)*16;
        const float* te=temb+m*16;
        for (int i=0;i<16;i++) g += W[i]*te[i];
        if (c<64) modsc[lvl*576+m*64+c]=1.0f+g+emb[(lvl*8+lvl)*64+c];
        else      modbi[lvl*576+m*64+(c-64)]=g;
    }
}

// ---------------- MFMA fused FULL RK4 step, 32-pos tiles --------------------
// grid (64, 8, 4): (32-pos tile, batch, level). block 256 = 4 waves.
// Tile frame: row R in [0,48) <-> pos l0-8+R. Central output R in [8,40).
// Halo shrinks 2/side per eval: k_e valid on R in [2e+2, 46-2e).
// VERIFIED-BEST config (R9: 106 us/dispatch, VGPR 84, FETCH 45 MB, no spill).
// Ledger of rejected variants (do NOT retry):
//  - launch_bounds (256,4)/(256,5): arch-VGPR cap ~= 256/waves < 96 weight
//    regs -> guaranteed scratch spill (0.65-1.0 GB traffic).
//  - ye in registers: +12 live regs at frozen cap 84 -> spill (+48 MB).
//  - LDS XOR swizzle / row-offset: SQ_LDS_BANK_CONFLICT ~8M is the
//    STRUCTURAL cost of wave64 ds_read_b128 (1024 B vs 128 B/cycle = 8
//    LDS cycles); no address permutation removes it; both attempts added
//    addressing pressure and re-spilled.
//  - dywan-fold into filt: redundant per-block MLP + extra barriers cost
//    more than the 3 tiny launches saved (+66 us non-ODE).
// Kept: persistent conv weights (R4), fast_gelu/fast_silu (R9, -10% VALU),
// pk2bf packing, ye re-read from own LDS cells, 36-dword rows.
__global__ __launch_bounds__(256,3) void ode_rk4_step(
    const float* __restrict__ yinB, float* __restrict__ youtB,
    const short* __restrict__ WB, const float* __restrict__ c1bB,
    const float* __restrict__ c2bB,
    const float* __restrict__ modscB, const float* __restrict__ modbiB,
    const float* __restrict__ tsB, float* __restrict__ eoutB,
    int step, int do_energy)
{
    __shared__ unsigned Eh[48][36], El[48][36];   // current ye (bf16 hi/lo)
    __shared__ unsigned Hh[48][36];               // conv1 output h (hi only)
    __shared__ float red[4];
    const int tid=threadIdx.x;
    const int lvl=blockIdx.z, b=blockIdx.y;
    const int l0=blockIdx.x*32;
    const size_t loff=(size_t)lvl*NTOT;
    const float* yin = yinB + loff;
    float* yout = youtB + loff;
    const float dt = tsB[lvl*8+step+1]-tsB[lvl*8+step];
    const float dt6 = dt*(1.0f/6.0f);
    const int wv=tid>>6, lane=tid&63;
    const int n=lane&15, quad=lane>>4;
    const int m0=wv*16;
    const int qy0=wv*8+quad*2;   // packed-pair col for this thread's 4 chans

    // ---- stage y into split-bf16 transposed tile (48 rows, zero-padded) ----
    if (lane<48){
        int r=lane, l=l0-8+r;
        bool ok=(l>=0 && l<LSEQ);
        unsigned hw[8], lw[8];
        #pragma unroll
        for (int qq=0;qq<8;qq++){
            int q=wv*8+qq;
            float v0=0.f, v1=0.f;
            if (ok){
                size_t g0=(size_t)(b*64+2*q)*LSEQ+l;
                v0=yin[g0]; v1=yin[g0+LSEQ];
            }
            unsigned h=pk2bf(v0,v1);
            float f0=__uint_as_float(h<<16);
            float f1=__uint_as_float(h&0xffff0000u);
            hw[qq]=h;
            lw[qq]=pk2bf(v0-f0, v1-f1);
        }
        *(uint4*)&Eh[r][wv*8]   = make_uint4(hw[0],hw[1],hw[2],hw[3]);
        *(uint4*)&Eh[r][wv*8+4] = make_uint4(hw[4],hw[5],hw[6],hw[7]);
        *(uint4*)&El[r][wv*8]   = make_uint4(lw[0],lw[1],lw[2],lw[3]);
        *(uint4*)&El[r][wv*8+4] = make_uint4(lw[4],lw[5],lw[6],lw[7]);
    }

    // ---- persistent conv weights + biases (held in VGPRs across evals) ----
    const short* W1 = WB + (size_t)(lvl*2+0)*2*3*4096;
    const short* W2 = WB + (size_t)(lvl*2+1)*2*3*4096;
    short8 A1[3][2][2], A2[3][2][2];
    #pragma unroll
    for (int tap=0;tap<3;tap++)
        #pragma unroll
        for (int ks=0;ks<2;ks++)
            #pragma unroll
            for (int hl=0;hl<2;hl++){
                size_t off=(((size_t)hl*3+tap)*64+(m0+n))*64+ks*32+quad*8;
                A1[tap][ks][hl]=*(const short8*)(W1+off);
                A2[tap][ks][hl]=*(const short8*)(W2+off);
            }
    float bia[4], bib[4];
    #pragma unroll
    for (int reg=0;reg<4;reg++){
        bia[reg]=c1bB[lvl*64 + m0 + quad*4 + reg];
        bib[reg]=c2bB[lvl*64 + m0 + quad*4 + reg];
    }
    __syncthreads();

    // ---- own-cell original y in fp32 registers ----
    float yr[3][4], acc[3][4];
    #pragma unroll
    for (int nt=0;nt<3;nt++){
        int R=16*nt+n;
        uint2 hh=*(const uint2*)&Eh[R][qy0];
        uint2 ll=*(const uint2*)&El[R][qy0];
        yr[nt][0]=bf2f(hh.x)+bf2f(ll.x);
        yr[nt][1]=bf2f(hh.x>>16)+bf2f(ll.x>>16);
        yr[nt][2]=bf2f(hh.y)+bf2f(ll.y);
        yr[nt][3]=bf2f(hh.y>>16)+bf2f(ll.y>>16);
        #pragma unroll
        for (int reg=0;reg<4;reg++) acc[nt][reg]=0.f;
    }

    float esum=0.f;
    #pragma unroll 1
    for (int e=0;e<4;e++){
        const int hLo=2*e+1, hHi=47-2*e;
        const int kLo=2*e+2, kHi=46-2*e;

        // ---- conv1 ----
        #pragma unroll
        for (int nt=0;nt<3;nt++){
            float4v d={bia[0],bia[1],bia[2],bia[3]};
            #pragma unroll
            for (int tap=0;tap<3;tap++){
                int rr=16*nt+n+tap-1;
                rr=(rr<0)?0:((rr>47)?47:rr);   // clamp (junk rows masked)
                const unsigned* ph=&Eh[rr][0];
                const unsigned* pl=&El[rr][0];
                #pragma unroll
                for (int ks=0;ks<2;ks++){
                    short8 bh=*(const short8*)(ph+ks*16+quad*4);
                    short8 bl=*(const short8*)(pl+ks*16+quad*4);
                    d=__builtin_amdgcn_mfma_f32_16x16x32_bf16(A1[tap][ks][0],bh,d,0,0,0);
                    d=__builtin_amdgcn_mfma_f32_16x16x32_bf16(A1[tap][ks][0],bl,d,0,0,0);
                    d=__builtin_amdgcn_mfma_f32_16x16x32_bf16(A1[tap][ks][1],bh,d,0,0,0);
                }
            }
            int R=16*nt+n, hp=l0-8+R;
            bool okh=(R>=hLo && R<hHi && hp>=0 && hp<LSEQ);
            float h0=okh?fast_gelu(d[0]):0.f;
            float h1=okh?fast_gelu(d[1]):0.f;
            float h2=okh?fast_gelu(d[2]):0.f;
            float h3=okh?fast_gelu(d[3]):0.f;
            uint2 hv;
            hv.x=pk2bf(h0,h1);
            hv.y=pk2bf(h2,h3);
            *(uint2*)&Hh[R][qy0]=hv;
        }
        __syncthreads();

        // ---- conv2 + epilogue (k fp32; ye from own LDS cells) ----
        {
            const int tslot=2*step+((e==0)?0:((e==3)?2:1));
            float sc[4], bi2[4];
            #pragma unroll
            for (int reg=0;reg<4;reg++){
                int co=m0+quad*4+reg;
                sc[reg] =modscB[lvl*576+tslot*64+co];
                bi2[reg]=modbiB[lvl*576+tslot*64+co];
            }
            const float alf=(e==2)?dt:0.5f*dt;
            const float wk=(e==0)?1.f:2.f;
            #pragma unroll
            for (int nt=0;nt<3;nt++){
                float4v d={bib[0],bib[1],bib[2],bib[3]};
                #pragma unroll
                for (int tap=0;tap<3;tap++){
                    int rr=16*nt+n+tap-1;
                    rr=(rr<0)?0:((rr>47)?47:rr);
                    const unsigned* ph=&Hh[rr][0];
                    #pragma unroll
                    for (int ks=0;ks<2;ks++){
                        short8 bh=*(const short8*)(ph+ks*16+quad*4);
                        d=__builtin_amdgcn_mfma_f32_16x16x32_bf16(A2[tap][ks][0],bh,d,0,0,0);
                        d=__builtin_amdgcn_mfma_f32_16x16x32_bf16(A2[tap][ks][1],bh,d,0,0,0);
                    }
                }
                int R=16*nt+n, p=l0-8+R;
                bool okk=(R>=kLo && R<kHi && p>=0 && p<LSEQ);
                bool central=(R>=8 && R<40);
                // ye from own LDS cells (self-written, self-read: no race)
                uint2 hh=*(const uint2*)&Eh[R][qy0];
                uint2 ll=*(const uint2*)&El[R][qy0];
                float yev[4];
                yev[0]=bf2f(hh.x)+bf2f(ll.x);
                yev[1]=bf2f(hh.x>>16)+bf2f(ll.x>>16);
                yev[2]=bf2f(hh.y)+bf2f(ll.y);
                yev[3]=bf2f(hh.y>>16)+bf2f(ll.y>>16);
                float kv[4];
                #pragma unroll
                for (int reg=0;reg<4;reg++){
                    float m=d[reg]*sc[reg]+bi2[reg];
                    kv[reg]=fast_silu(m)-0.1f*yev[reg];
                }
                if (e<3){
                    float z[4];
                    #pragma unroll
                    for (int reg=0;reg<4;reg++)
                        z[reg]=okk?(yr[nt][reg]+alf*kv[reg]):0.f;
                    uint2 ev, lv;
                    ev.x=pk2bf(z[0],z[1]);
                    ev.y=pk2bf(z[2],z[3]);
                    float f0=__uint_as_float(ev.x<<16);
                    float f1=__uint_as_float(ev.x&0xffff0000u);
                    float f2=__uint_as_float(ev.y<<16);
                    float f3=__uint_as_float(ev.y&0xffff0000u);
                    lv.x=pk2bf(z[0]-f0, z[1]-f1);
                    lv.y=pk2bf(z[2]-f2, z[3]-f3);
                    *(uint2*)&Eh[R][qy0]=ev;
                    *(uint2*)&El[R][qy0]=lv;
                    if (central){
                        #pragma unroll
                        for (int reg=0;reg<4;reg++) acc[nt][reg]+=wk*kv[reg];
                    }
                } else if (central){
                    size_t gbase=(size_t)(b*64+m0+quad*4)*LSEQ+p;
                    #pragma unroll
                    for (int reg=0;reg<4;reg++){
                        float yn=yr[nt][reg]+dt6*(acc[nt][reg]+kv[reg]);
                        yout[gbase+(size_t)reg*LSEQ]=yn;
                        esum+=yn*yn;
                    }
                }
            }
        }
        __syncthreads();
    }
    if (do_energy){
        for (int o=32;o>0;o>>=1) esum+=__shfl_down(esum,o,64);
        if ((tid&63)==0) red[tid>>6]=esum;
        __syncthreads();
        if (tid==0) atomicAdd(&eoutB[lvl*8+b], red[0]+red[1]+red[2]+red[3]);
    }
}

// -------- fused reconstruction: scale + [attn] + gate + residual ------------
// grid (32, NB). cur scaled by s(lvl_cur) on load (if lvl_cur>=0);
// detail read from det_in scaled by s(lvl_det); final detail written to det_out.
__global__ __launch_bounds__(256) void recon_kernel(
    const float* __restrict__ cur, const float* __restrict__ det_in,
    float* __restrict__ det_out,
    const float* __restrict__ a1w, const float* __restrict__ a1b,
    const float* __restrict__ a2w, const float* __restrict__ a2b,
    const float* __restrict__ gwt, const float* __restrict__ gb,
    float* __restrict__ curout,
    const float* __restrict__ ein, const float* __restrict__ eout,
    int lvl_cur, int lvl_det, int has_attn)
{
    __shared__ float yc[64][66];
    __shared__ float dtile[64][65];
    __shared__ float hid[16][64];
    const int tid=threadIdx.x, b=blockIdx.y, l0=blockIdx.x*64;
    float scur=1.f, sdet;
    if (lvl_cur>=0){
        float eo=eout[lvl_cur*8+b]*(1.0f/131072.0f);
        scur=sqrtf(ein[lvl_cur*8+b]/(eo+1e-8f));
    }
    {
        float eo=eout[lvl_det*8+b]*(1.0f/131072.0f);
        sdet=sqrtf(ein[lvl_det*8+b]/(eo+1e-8f));
    }
    for (int idx=tid; idx<64*66; idx+=256){
        int ci=idx/66, u=idx-ci*66;
        int l=l0+u-1;
        yc[ci][u]=(l>=0 && l<LSEQ)? scur*cur[(size_t)(b*64+ci)*LSEQ+l] : 0.f;
    }
    for (int idx=tid; idx<4096; idx+=256){
        int ci=idx>>6, p=idx&63;
        dtile[ci][p]=sdet*det_in[(size_t)(b*64+ci)*LSEQ+l0+p];
    }
    __syncthreads();
    if (has_attn){
        for (int idx=tid; idx<1024; idx+=256){
            int h=idx>>6, p=idx&63;
            float acc=a1b[h];
            const float* W=a1w+h*64;
            for (int ci=0;ci<64;ci++) acc += W[ci]*yc[ci][p+1];
            hid[h][p]=geluf(acc);
        }
        __syncthreads();
        for (int idx=tid; idx<4096; idx+=256){
            int co=idx>>6, p=idx&63;
            float acc=a2b[co];
            const float* W=a2w+co*16;
            #pragma unroll
            for (int h=0;h<16;h++) acc += W[h]*hid[h][p];
            float a=sigf(acc);
            float dnew = dtile[co][p]*(1.0f+a);
            dtile[co][p]=dnew;
            det_out[(size_t)(b*64+co)*LSEQ+l0+p]=dnew;
        }
        __syncthreads();
    } else {
        for (int idx=tid; idx<4096; idx+=256){
            int ci=idx>>6, p=idx&63;
            det_out[(size_t)(b*64+ci)*LSEQ+l0+p]=dtile[ci][p];
        }
    }
    const int co=tid&63, g=tid>>6;
    const int p0=g*16;
    float a[16];
    float bb=gb[co];
    #pragma unroll
    for (int i=0;i<16;i++) a[i]=bb;
    for (int ci=0;ci<64;ci++){
        float w0=gwt[(ci*3+0)*64+co];
        float w1_=gwt[(ci*3+1)*64+co];
        float w2_=gwt[(ci*3+2)*64+co];
        float x[18];
        #pragma unroll
        for (int j=0;j<18;j++) x[j]=yc[ci][p0+j];
        #pragma unroll
        for (int i=0;i<16;i++) a[i] += w0*x[i]+w1_*x[i+1]+w2_*x[i+2];
    }
    float r[16];
    #pragma unroll
    for (int i=0;i<16;i++){
        float gt=sigf(a[i]);
        r[i]=yc[co][p0+i+1]+gt*dtile[co][p0+i];
    }
    __syncthreads();
    #pragma unroll
    for (int i=0;i<16;i++) dtile[co][p0+i]=r[i];
    __syncthreads();
    for (int idx=tid; idx<4096; idx+=256){
        int ci=idx>>6, p=idx&63;
        curout[(size_t)(b*64+ci)*LSEQ+l0+p]=dtile[ci][p];
    }
}

extern "C" void kernel_launch(void* const* d_in, const int* in_sizes, int n_in,
                              void* d_out, int out_size, void* d_ws, size_t ws_size,
                              hipStream_t stream)
{
    (void)in_sizes; (void)n_in; (void)out_size; (void)ws_size;
    const float* x       =(const float*)d_in[0];
    const float* dy_w1   =(const float*)d_in[1];
    const float* dy_b1   =(const float*)d_in[2];
    const float* dy_wg1  =(const float*)d_in[3];
    const float* dy_bg1  =(const float*)d_in[4];
    const float* dy_wg2  =(const float*)d_in[5];
    const float* dy_bg2  =(const float*)d_in[6];
    const float* ode_c1w =(const float*)d_in[7];
    const float* ode_c1b =(const float*)d_in[8];
    const float* ode_c2w =(const float*)d_in[9];
    const float* ode_c2b =(const float*)d_in[10];
    const float* ode_wt  =(const float*)d_in[11];
    const float* ode_bt  =(const float*)d_in[12];
    const float* ode_wm  =(const float*)d_in[13];
    const float* ode_bm  =(const float*)d_in[14];
    const float* ode_emb =(const float*)d_in[15];
    const float* gate_w  =(const float*)d_in[16];
    const float* gate_b  =(const float*)d_in[17];
    const float* attn1_w =(const float*)d_in[18];
    const float* attn1_b =(const float*)d_in[19];
    const float* attn2_w =(const float*)d_in[20];
    const float* attn2_b =(const float*)d_in[21];
    float* out=(float*)d_out;
    float* ws=(float*)d_ws;
    const size_t N=NTOT;
    // workspace layout (floats)
    float* CB = ws;                      // coeff[4]: A0, D1, D2, D3 (4N)
    float* PB = ws+4*N;                  // y ping (4 levels) — also decomp temps
    float* QB = ws+8*N;                  // y pong (4 levels)
    float* SM = ws+20*N;
    float* stat_ws =SM;          // 512
    float* lo_ws   =SM+512;      // 64
    float* hi_ws   =SM+576;      // 64
    float* rowstats=SM+1024;     // 4*512*8 = 16384
    float* ts_ws   =SM+17408;    // 4*8
    float* modsc   =SM+17536;    // 4*576
    float* modbi   =SM+19840;    // 4*576
    float* ein     =SM+22144;    // 32
    float* eoutb   =SM+22176;    // 32
    short* WB      =(short*)(SM+24576);  // 393216 bf16 = 196608 floats
    float* WTG     =SM+24576+196608;     // 3*12288 (gate weights, transposed)

    dim3 blk(256);

    wprep_kernel<<<768,blk,0,stream>>>(ode_c1w, ode_c2w, WB);
    for (int i=0;i<3;i++)
        wtrans_kernel<<<48,blk,0,stream>>>(gate_w+(size_t)i*12288, WTG+(size_t)i*12288);

    // ---- wavelet decomposition (3 levels, sequential; stat fused in filt) --
    stat_kernel<<<NROWS,blk,0,stream>>>(x, stat_ws);
    const float* cura=x;
    float* outsA[3]={PB, PB+N, CB};      // T0, T1, A0-final
    float* outsD[3]={CB+N, CB+2*N, CB+3*N};
    for (int lv=0; lv<3; lv++){
        dywan_kernel<<<1,blk,0,stream>>>(stat_ws, dy_w1,dy_b1,dy_wg1,dy_bg1,dy_wg2,dy_bg2,
                                         lo_ws, hi_ws, out+4*N);
        float* statn = (lv<2)? stat_ws : nullptr;
        filt_kernel<<<dim3(8,NROWS),blk,0,stream>>>(cura, lo_ws, hi_ws,
                                                    outsA[lv], outsD[lv], statn);
        cura=outsA[lv];
    }

    // ---- adaptive grids + modulation for all 4 levels ----
    tg_pass1<<<dim3(NROWS,4),blk,0,stream>>>(CB, rowstats);
    tg_finalize<<<4,blk,0,stream>>>(rowstats, ode_wt, ode_bt, ode_wm, ode_bm,
                                    ode_emb, ts_ws, modsc, modbi, ein, eoutb);

    // ---- RK4: 4 fused steps (each does all 4 evals in-block) ----
    const float* yins[4]={CB, PB, QB, PB};
    float*       youts[4]={PB, QB, PB, QB};
    for (int s=0;s<4;s++){
        ode_rk4_step<<<dim3(64,NB,4),blk,0,stream>>>(
            yins[s], youts[s], WB, ode_c1b, ode_c2b,
            modsc, modbi, ts_ws, eoutb, s, (s==3)?1:0);
    }

    // ---- reconstruction (fused scale+attn+gate); evolved lives in QB ----
    // i=2: cur=s0*QB0, detail=s3*QB3 -> out3; current -> PB
    recon_kernel<<<dim3(32,NB),blk,0,stream>>>(QB+0*N, QB+3*N, out+3*N,
        attn1_w, attn1_b, attn2_w, attn2_b,
        WTG+2*12288, gate_b+128, PB, ein, eoutb, 0, 3, 0);
    // i=1: cur=PB, detail=s2*QB2 + attn(set1) -> out2; current -> QB(slot0)
    recon_kernel<<<dim3(32,NB),blk,0,stream>>>(PB, QB+2*N, out+2*N,
        attn1_w+1024, attn1_b+16, attn2_w+1024, attn2_b+64,
        WTG+1*12288, gate_b+64, QB, ein, eoutb, -1, 2, 1);
    // i=0: cur=QB(slot0), detail=s1*QB1 + attn(set0) -> out1; current -> out0
    recon_kernel<<<dim3(32,NB),blk,0,stream>>>(QB, QB+1*N, out+1*N,
        attn1_w, attn1_b, attn2_w, attn2_b,
        WTG, gate_b, out+0*N, ein, eoutb, -1, 1, 1);
}